// Round 3
// baseline (232.015 us; speedup 1.0000x reference)
//
#include <hip/hip_runtime.h>

// RollScheduler forward: out[b,c,k] = clips[b,c,k-idx] for k>=idx else 0,
// idx = trunc(x[b,c] * N). Pure memory-bound shift-right per row.
// B=C=32, N=32768, fp32. `actual` input is unused in forward.

constexpr int N_SAMPLES = 32768;
constexpr int BLOCK = 256;

__global__ __launch_bounds__(BLOCK) void roll_place_kernel(
    const float* __restrict__ x,      // (B*C,)
    const float* __restrict__ clips,  // (B*C, N)
    float* __restrict__ out)          // (B*C, N)
{
    const int row = blockIdx.x;
    // Truncation matches astype(int32); x*2^15 is exact in fp32.
    int idx = (int)(x[row] * (float)N_SAMPLES);
    // x in [0,1) so idx in [0, N-1]; clamp defensively.
    idx = idx < 0 ? 0 : (idx > N_SAMPLES ? N_SAMPLES : idx);

    const float* __restrict__ src = clips + (size_t)row * N_SAMPLES;
    float* __restrict__ dst = out + (size_t)row * N_SAMPLES;

    const int tid = threadIdx.x;
    constexpr int NV = N_SAMPLES / 4;  // float4 chunks per row

    #pragma unroll 4
    for (int v = tid; v < NV; v += BLOCK) {
        const int k0 = v * 4;
        float4 r;
        if (k0 >= idx) {
            // Fully in the copied region. Reads misaligned by idx%4 ->
            // 4 scalar dword loads; union across the wave is contiguous.
            const float* p = src + (k0 - idx);
            r.x = p[0];
            r.y = p[1];
            r.z = p[2];
            r.w = p[3];
        } else if (k0 + 3 < idx) {
            // Fully in the zero region: no load at all.
            r = make_float4(0.f, 0.f, 0.f, 0.f);
        } else {
            // Boundary chunk (one per row at most).
            float vals[4];
            #pragma unroll
            for (int j = 0; j < 4; ++j) {
                const int k = k0 + j;
                vals[j] = (k >= idx) ? src[k - idx] : 0.f;
            }
            r = make_float4(vals[0], vals[1], vals[2], vals[3]);
        }
        // Aligned 16B store.
        *reinterpret_cast<float4*>(dst + k0) = r;
    }
}

extern "C" void kernel_launch(void* const* d_in, const int* in_sizes, int n_in,
                              void* d_out, int out_size, void* d_ws, size_t ws_size,
                              hipStream_t stream) {
    const float* x     = (const float*)d_in[0];  // (B, C) = 1024 positions
    const float* clips = (const float*)d_in[1];  // (B, C, N)
    // d_in[2] = actual, unused in forward.
    float* out = (float*)d_out;                  // (B, C, N) fp32

    const int rows = in_sizes[0];                // B*C = 1024
    roll_place_kernel<<<rows, BLOCK, 0, stream>>>(x, clips, out);
}